// Round 1
// baseline (276.348 us; speedup 1.0000x reference)
//
#include <hip/hip_runtime.h>
#include <hip/hip_bf16.h>

typedef unsigned short u16;
typedef unsigned int u32;
typedef __attribute__((ext_vector_type(8))) short bf16x8;   // 8 bf16 (4 VGPRs)
typedef __attribute__((ext_vector_type(4))) float f32x4;

#define NL 2048
#define NH 16
// HD = 64; scale 1/8 and log2(e) folded into Q pre-scale

__device__ __forceinline__ float bf2f(u16 v) {
    union { float f; unsigned u; } x; x.u = ((unsigned)v) << 16; return x.f;
}
__device__ __forceinline__ u16 f2bf(float f) {
    union { __hip_bfloat16 h; u16 u; } x; x.h = __float2bfloat16(f); return x.u;
}
// round-half-up pack of two fp32 -> packed bf16 pair (finite inputs)
__device__ __forceinline__ u32 pk2(float a, float b) {
    union { float f; u32 u; } x, y; x.f = a; y.f = b;
    return ((x.u + 0x8000u) >> 16) | ((y.u + 0x8000u) & 0xffff0000u);
}
// truncating pack (1 VALU op): {hi16(hi), hi16(lo)} via v_perm_b32. Only for P:
// L is summed from the same packed values -> bias cancels in O = sum(pV)/sum(p).
__device__ __forceinline__ u32 pkt(float lo, float hi) {
    union { float f; u32 u; } x, y; x.f = lo; y.f = hi;
    return __builtin_amdgcn_perm(y.u, x.u, 0x07060302u);
}
#if __has_builtin(__builtin_amdgcn_exp2f)
#define EXP2F(x) __builtin_amdgcn_exp2f(x)
#else
#define EXP2F(x) __expf((x) * 0.69314718056f)
#endif

// async global->LDS, 16B per lane; LDS dest = wave-uniform base + lane*16
__device__ __forceinline__ void gload_lds16(const u16* g, u16* l) {
    __builtin_amdgcn_global_load_lds(
        (__attribute__((address_space(1))) void*)(g),
        (__attribute__((address_space(3))) void*)(l), 16, 0, 0);
}

// --------------------------------------- fp32 -> bf16 cast, all 3 inputs fused
__global__ __launch_bounds__(256) void cast_all_k(const float* __restrict__ x,
                                                  const float* __restrict__ wq,
                                                  const float* __restrict__ wp,
                                                  u16* __restrict__ xo,
                                                  u16* __restrict__ wqo,
                                                  u16* __restrict__ wpo) {
    int i = blockIdx.x * 256 + threadIdx.x;      // 0..3145727 (x4 elems)
    const float* src; u16* dst; int off;
    if (i < 2097152)      { src = x;  dst = xo;  off = i; }
    else if (i < 2883584) { src = wq; dst = wqo; off = i - 2097152; }
    else                  { src = wp; dst = wpo; off = i - 2883584; }
    float4 v = *(const float4*)&src[(size_t)off * 4];
    u16 tmp[4] = {f2bf(v.x), f2bf(v.y), f2bf(v.z), f2bf(v.w)};
    *(ushort4*)&dst[(size_t)off * 4] = *(ushort4*)tmp;
}

// ---------------------------------------------------------------- rope table
__global__ __launch_bounds__(256) void rope_table_k(float* __restrict__ cosT,
                                                    float* __restrict__ sinT) {
    int idx = blockIdx.x * 256 + threadIdx.x;    // L*32 = 65536
    int l = idx >> 5, i = idx & 31;
    float invf = exp2f(-(float)i * 0.41524101186092029f);  // log2(10000)/32
    float ang = (float)l * invf;
    cosT[idx] = cosf(ang);
    sinT[idx] = sinf(ang);
}

// ---------------------------------------------------- NT GEMM: C = A * B^T
// A [M][K] bf16, B [N][K] bf16, C [M][N] (bf16 or fp32). M%128, N%128, K%64 == 0.
// Staging via global_load_lds(16B); unpadded LDS with XOR chunk swizzle.
template <typename OutT>
__global__ __launch_bounds__(256) void gemm_bt(const u16* __restrict__ A,
                                               const u16* __restrict__ Bm,
                                               OutT* __restrict__ C,
                                               int M, int N, int K) {
    __shared__ u16 As[128][64];
    __shared__ u16 Bs[128][64];
    const int t = threadIdx.x;
    const int lane = t & 63, wave = t >> 6;
    const int quad = lane >> 4, lrow = lane & 15;
    const int wr = wave >> 1, wc = wave & 1;
    const size_t m0 = (size_t)blockIdx.y * 128, n0 = (size_t)blockIdx.x * 128;

    const int srow = wave * 32 + (lane >> 3);       // +j*8 covers 32 rows/wave
    const int scg  = (lane & 7) ^ (lane >> 3);      // swizzled global chunk

    f32x4 acc[4][4];
#pragma unroll
    for (int i = 0; i < 4; ++i)
#pragma unroll
        for (int j = 0; j < 4; ++j) acc[i][j] = (f32x4)0.0f;

    for (int k0 = 0; k0 < K; k0 += 64) {
#pragma unroll
        for (int j = 0; j < 4; ++j) {
            gload_lds16(&A[(m0 + srow + j * 8) * K + k0 + scg * 8],
                        &As[wave * 32 + j * 8][0]);
            gload_lds16(&Bm[(n0 + srow + j * 8) * K + k0 + scg * 8],
                        &Bs[wave * 32 + j * 8][0]);
        }
        __syncthreads();
#pragma unroll
        for (int ks = 0; ks < 2; ++ks) {
            bf16x8 av[4], bv[4];
#pragma unroll
            for (int i = 0; i < 4; ++i)
                av[i] = *(const bf16x8*)
                    &As[wr * 64 + i * 16 + lrow][(((ks << 2) | quad) ^ (lrow & 7)) << 3];
#pragma unroll
            for (int j = 0; j < 4; ++j)
                bv[j] = *(const bf16x8*)
                    &Bs[wc * 64 + j * 16 + lrow][(((ks << 2) | quad) ^ (lrow & 7)) << 3];
#pragma unroll
            for (int i = 0; i < 4; ++i)
#pragma unroll
                for (int j = 0; j < 4; ++j)
                    acc[i][j] = __builtin_amdgcn_mfma_f32_16x16x32_bf16(
                        av[i], bv[j], acc[i][j], 0, 0, 0);
        }
        __syncthreads();
    }
    // C/D layout: col = lane&15, row = quad*4 + r
#pragma unroll
    for (int i = 0; i < 4; ++i)
#pragma unroll
        for (int r = 0; r < 4; ++r) {
            size_t row = m0 + wr * 64 + i * 16 + quad * 4 + r;
#pragma unroll
            for (int j = 0; j < 4; ++j) {
                size_t col = n0 + wc * 64 + j * 16 + lrow;
                if constexpr (sizeof(OutT) == 4)
                    C[row * N + col] = acc[i][j][r];
                else
                    C[row * N + col] = f2bf(acc[i][j][r]);
            }
        }
}

// --------------- fused RoPE(q,k) + V-transpose: one pass over the qkv buffer
// grid (32 l-tiles, 64 bh), 256 thr. Q,K -> [BH][L][64] rope'd; V -> VT [BH*64][L].
__global__ __launch_bounds__(256) void rope_vt_k(const u16* __restrict__ qkv,
                                                 const float* __restrict__ cosT,
                                                 const float* __restrict__ sinT,
                                                 u16* __restrict__ Q,
                                                 u16* __restrict__ Ko,
                                                 u16* __restrict__ VT) {
    __shared__ u16 vtile[64][72];
    const int lt = blockIdx.x, bh = blockIdx.y;
    const int b = bh >> 4, h = bh & 15;
    const int l0 = lt * 64;
    const int t = threadIdx.x;
    const float SC = 0.180336879f;       // 1/8 * log2(e): exp2-ready logits
#pragma unroll
    for (int c = 0; c < 2; ++c) {
        int flat8 = c * 256 + t;         // 0..511
        int li = flat8 >> 3, dg = flat8 & 7;
        const u16* rowp = qkv + (size_t)(b * NL + l0 + li) * 3072 + h * 64 + dg * 8;
        uint4 qv = *(const uint4*)rowp;
        uint4 kv = *(const uint4*)(rowp + 1024);
        uint4 vv = *(const uint4*)(rowp + 2048);
        *(uint4*)&vtile[li][dg * 8] = vv;
        float4 cs = *(const float4*)&cosT[(l0 + li) * 32 + dg * 4];
        float4 sn = *(const float4*)&sinT[(l0 + li) * 32 + dg * 4];
        union { float f; u32 u; } w;
        float e0, o0, e1, o1, e2, o2, e3, o3;
        w.u = qv.x << 16; e0 = w.f; w.u = qv.x & 0xffff0000u; o0 = w.f;
        w.u = qv.y << 16; e1 = w.f; w.u = qv.y & 0xffff0000u; o1 = w.f;
        w.u = qv.z << 16; e2 = w.f; w.u = qv.z & 0xffff0000u; o2 = w.f;
        w.u = qv.w << 16; e3 = w.f; w.u = qv.w & 0xffff0000u; o3 = w.f;
        float c0 = cs.x * SC, c1 = cs.y * SC, c2 = cs.z * SC, c3 = cs.w * SC;
        float s0 = sn.x * SC, s1 = sn.y * SC, s2 = sn.z * SC, s3 = sn.w * SC;
        size_t ob = ((size_t)(b * NH + h) * NL + l0 + li) * 64;
        *(uint2*)&Q[ob + dg * 4] =
            make_uint2(pk2(e0 * c0 - o0 * s0, e1 * c1 - o1 * s1),
                       pk2(e2 * c2 - o2 * s2, e3 * c3 - o3 * s3));
        *(uint2*)&Q[ob + 32 + dg * 4] =
            make_uint2(pk2(e0 * s0 + o0 * c0, e1 * s1 + o1 * c1),
                       pk2(e2 * s2 + o2 * c2, e3 * s3 + o3 * c3));
        float f0, g0, f1, g1, f2, g2, f3, g3;
        w.u = kv.x << 16; f0 = w.f; w.u = kv.x & 0xffff0000u; g0 = w.f;
        w.u = kv.y << 16; f1 = w.f; w.u = kv.y & 0xffff0000u; g1 = w.f;
        w.u = kv.z << 16; f2 = w.f; w.u = kv.z & 0xffff0000u; g2 = w.f;
        w.u = kv.w << 16; f3 = w.f; w.u = kv.w & 0xffff0000u; g3 = w.f;
        *(uint2*)&Ko[ob + dg * 4] =
            make_uint2(pk2(f0 * cs.x - g0 * sn.x, f1 * cs.y - g1 * sn.y),
                       pk2(f2 * cs.z - g2 * sn.z, f3 * cs.w - g3 * sn.w));
        *(uint2*)&Ko[ob + 32 + dg * 4] =
            make_uint2(pk2(f0 * sn.x + g0 * cs.x, f1 * sn.y + g1 * cs.y),
                       pk2(f2 * sn.z + g2 * cs.z, f3 * sn.w + g3 * cs.w));
    }
    __syncthreads();
#pragma unroll
    for (int c = 0; c < 2; ++c) {
        int flat8 = c * 256 + t;
        int d = flat8 >> 3, lg = flat8 & 7;
        u16 tmp[8];
#pragma unroll
        for (int e = 0; e < 8; ++e) tmp[e] = vtile[lg * 8 + e][d];
        *(uint4*)&VT[((size_t)(bh * 64 + d)) * NL + l0 + lg * 8] = *(uint4*)tmp;
    }
}

// --------------------------------------------- flash attention (MFMA)
// 256 q per block, 4 waves x 64 q (four 16-col halves qh=0..3 sharing every
// K/V fragment read -> 4x LDS arithmetic intensity; the kernel is LDS-pipe
// bound, not MFMA bound). S^T = K.Q^T (query in C/D column). Single barrier
// per chunk with K/V double-buffer prefetch. No online max (logits bounded);
// p = exp2(s), trunc-packed via v_perm, row-sum L via all-ones-A MFMA,
// single divide at the end.
__global__ __launch_bounds__(256, 2) void attn_k(const u16* __restrict__ Q,
                                                 const u16* __restrict__ Kg,
                                                 const u16* __restrict__ VT,
                                                 u16* __restrict__ Og) {
    __shared__ __align__(16) char smem[65536];
    u16 (*KsB)[64][64] = (u16(*)[64][64])(smem);           // 2 bufs @0, 8192
    u16 (*VsB)[64][64] = (u16(*)[64][64])(smem + 16384);   // 2 bufs @16384, 24576
    u16* PsBase = (u16*)(smem + 32768);                    // 4 waves x 8192 B
    const int t = threadIdx.x;
    const int lane = t & 63, wave = t >> 6;                // wave 0..3
    const int quad = lane >> 4, lq = lane & 15;
    u16* PsW = PsBase + wave * 4096;                       // [64 q][64 k] swz

    const int qt = blockIdx.x, bh = blockIdx.y;
    const int q0 = qt * 256;
    const size_t qkbase = (size_t)bh * NL * 64;

    const int rsub = lane >> 3;                            // 0..7
    const int scg  = (lane & 7) ^ rsub;                    // swizzled global chunk

    // preloop: stage Q (256x64, through Ps region) + prefetch chunk 0
    u16 (*Qtmp)[64] = (u16(*)[64])(smem + 32768);
#pragma unroll
    for (int j = 0; j < 8; ++j)
        gload_lds16(&Q[qkbase + (size_t)(q0 + wave * 64 + j * 8 + rsub) * 64 + scg * 8],
                    &Qtmp[wave * 64 + j * 8][0]);
    const u16* kptr = Kg + qkbase + (size_t)(wave * 16 + rsub) * 64 + scg * 8;
    const u16* vptr = VT + qkbase + (size_t)(wave * 16 + rsub) * NL + scg * 8;
    gload_lds16(kptr, &KsB[0][wave * 16][0]);
    gload_lds16(kptr + 8 * 64, &KsB[0][wave * 16 + 8][0]);
    gload_lds16(vptr, &VsB[0][wave * 16][0]);
    gload_lds16(vptr + (size_t)8 * NL, &VsB[0][wave * 16 + 8][0]);
    kptr += 64 * 64;
    vptr += 64;
    __syncthreads();                      // Q + chunk0 resident
    bf16x8 bq[4][2];                      // Q frags: invariant across chunks
#pragma unroll
    for (int qh = 0; qh < 4; ++qh)
#pragma unroll
        for (int ks = 0; ks < 2; ++ks)
            bq[qh][ks] = *(const bf16x8*)
                &Qtmp[wave * 64 + qh * 16 + lq][(((ks << 2) | quad) ^ (lq & 7)) << 3];

    const bf16x8 ones = (bf16x8)(short)16256;              // bf16 1.0 splat
    f32x4 ot[4][4];                       // O^T rows d = mt*16+quad*4+r
#pragma unroll
    for (int qh = 0; qh < 4; ++qh)
#pragma unroll
        for (int mt = 0; mt < 4; ++mt) ot[qh][mt] = (f32x4)0.0f;
    f32x4 lacc[4] = {(f32x4)0.0f, (f32x4)0.0f, (f32x4)0.0f, (f32x4)0.0f};

    for (int kc = 0; kc < NL / 64; ++kc) {
        __syncthreads();                  // prev chunk consumed; prefetch landed
        if (kc < NL / 64 - 1) {
            gload_lds16(kptr, &KsB[(kc + 1) & 1][wave * 16][0]);
            gload_lds16(kptr + 8 * 64, &KsB[(kc + 1) & 1][wave * 16 + 8][0]);
            gload_lds16(vptr, &VsB[(kc + 1) & 1][wave * 16][0]);
            gload_lds16(vptr + (size_t)8 * NL, &VsB[(kc + 1) & 1][wave * 16 + 8][0]);
            kptr += 64 * 64;
            vptr += 64;
        }
        const int cur = kc & 1;

        // S^T = K_chunk (64k x 64d) . Q^T (64d x 64q); K frag feeds 4 halves
        f32x4 st[4][4];
#pragma unroll
        for (int qh = 0; qh < 4; ++qh)
#pragma unroll
            for (int mt = 0; mt < 4; ++mt) st[qh][mt] = (f32x4)0.0f;
#pragma unroll
        for (int ks = 0; ks < 2; ++ks)
#pragma unroll
            for (int mt = 0; mt < 4; ++mt) {
                bf16x8 ak = *(const bf16x8*)
                    &KsB[cur][mt * 16 + lq][(((ks << 2) | quad) ^ (lq & 7)) << 3];
#pragma unroll
                for (int qh = 0; qh < 4; ++qh)
                    st[qh][mt] = __builtin_amdgcn_mfma_f32_16x16x32_bf16(
                        ak, bq[qh][ks], st[qh][mt], 0, 0, 0);
            }

        // p = exp2(s); 1-op trunc pack; swizzled uint2 stores to Ps
#pragma unroll
        for (int qh = 0; qh < 4; ++qh)
#pragma unroll
            for (int mt = 0; mt < 4; ++mt) {
                int pblk = (mt * 2 + (quad >> 1)) ^ (lq & 7);
                *(uint2*)&PsW[(qh * 16 + lq) * 64 + pblk * 8 + (quad & 1) * 4] =
                    make_uint2(pkt(EXP2F(st[qh][mt][0]), EXP2F(st[qh][mt][1])),
                               pkt(EXP2F(st[qh][mt][2]), EXP2F(st[qh][mt][3])));
            }
        __builtin_amdgcn_s_waitcnt(0xc07f);  // lgkmcnt(0): intra-wave LDS RAW

        // O^T += V^T_chunk . P^T ; L += ones . P^T; V frag feeds 4 halves
#pragma unroll
        for (int ks = 0; ks < 2; ++ks) {
            const int sw = (((ks << 2) | quad) ^ (lq & 7)) * 8;
            bf16x8 bp[4];
#pragma unroll
            for (int qh = 0; qh < 4; ++qh) {
                bp[qh] = *(const bf16x8*)&PsW[(qh * 16 + lq) * 64 + sw];
                lacc[qh] = __builtin_amdgcn_mfma_f32_16x16x32_bf16(
                    ones, bp[qh], lacc[qh], 0, 0, 0);
            }
#pragma unroll
            for (int mt = 0; mt < 4; ++mt) {
                bf16x8 av = *(const bf16x8*)
                    &VsB[cur][mt * 16 + lq][(((ks << 2) | quad) ^ (lq & 7)) << 3];
#pragma unroll
                for (int qh = 0; qh < 4; ++qh)
                    ot[qh][mt] = __builtin_amdgcn_mfma_f32_16x16x32_bf16(
                        av, bp[qh], ot[qh][mt], 0, 0, 0);
            }
        }
    }

    // epilogue: transpose O^T through LDS, one 16-q half at a time
    __syncthreads();
    float* OT_ls = (float*)(smem + wave * 4352);     // [64 d][17] floats, per wave
    float* Ls_ls = (float*)(smem + 17408);           // 4 waves x 16 q
    const int b = bh >> 4, h = bh & 15;
    const int qq = lane >> 2, dblk = lane & 3;       // 16 rows x 4 d-blocks
#pragma unroll
    for (int qh = 0; qh < 4; ++qh) {
#pragma unroll
        for (int mt = 0; mt < 4; ++mt)
#pragma unroll
            for (int r = 0; r < 4; ++r)
                OT_ls[(mt * 16 + quad * 4 + r) * 17 + lq] = ot[qh][mt][r];
        if (quad == 0) Ls_ls[wave * 16 + lq] = lacc[qh][0];
        __builtin_amdgcn_s_waitcnt(0xc07f);          // intra-wave LDS RAW

        float rls = 1.0f / Ls_ls[wave * 16 + qq];
        u16 tmp[16];
#pragma unroll
        for (int e = 0; e < 16; ++e)
            tmp[e] = f2bf(OT_ls[(dblk * 16 + e) * 17 + qq] * rls);
        size_t orow = (size_t)b * NL + q0 + wave * 64 + qh * 16 + qq;
        size_t obase = orow * 1024 + h * 64 + dblk * 16;
        *(uint4*)&Og[obase] = *(uint4*)&tmp[0];
        *(uint4*)&Og[obase + 8] = *(uint4*)&tmp[8];
    }
}

// ----------------------------------------------------------------- launch
extern "C" void kernel_launch(void* const* d_in, const int* in_sizes, int n_in,
                              void* d_out, int out_size, void* d_ws, size_t ws_size,
                              hipStream_t stream) {
    const float* x     = (const float*)d_in[0];   // [8192][1024] fp32
    const float* Wqkv  = (const float*)d_in[1];   // [3072][1024] fp32
    const float* Wproj = (const float*)d_in[2];   // [1024][1024] fp32
    float* out = (float*)d_out;                   // [8192][1024] fp32

    char* ws = (char*)d_ws;
    u16* qkv     = (u16*)ws;                      // 50,331,648 B
    u16* attnout = (u16*)ws;                      // reuses qkv region (dead by then)
    u16* Qw      = (u16*)(ws + 50331648);         // 16,777,216 B
    u16* Kw      = (u16*)(ws + 67108864);         // 16,777,216 B
    u16* VTw     = (u16*)(ws + 83886080);         // 16,777,216 B
    float* cosT  = (float*)(ws + 100663296);      //    262,144 B
    float* sinT  = (float*)(ws + 100925440);      //    262,144 B
    u16* x_bf    = (u16*)(ws + 101187584);        // 16,777,216 B
    u16* Wqkv_bf = (u16*)(ws + 117964800);        //  6,291,456 B
    u16* Wproj_bf= (u16*)(ws + 124256256);        //  2,097,152 B  (total ~126.4 MB)

    rope_table_k<<<256, 256, 0, stream>>>(cosT, sinT);
    cast_all_k<<<12288, 256, 0, stream>>>(x, Wqkv, Wproj, x_bf, Wqkv_bf, Wproj_bf);
    gemm_bt<u16><<<dim3(24, 64), 256, 0, stream>>>(x_bf, Wqkv_bf, qkv, 8192, 3072, 1024);
    rope_vt_k<<<dim3(32, 64), 256, 0, stream>>>(qkv, cosT, sinT, Qw, Kw, VTw);
    attn_k<<<dim3(8, 64), 256, 0, stream>>>(Qw, Kw, VTw, attnout);
    gemm_bt<float><<<dim3(8, 64), 256, 0, stream>>>(attnout, Wproj_bf, out, 8192, 1024, 1024);
}

// Round 2
// 265.740 us; speedup vs baseline: 1.0399x; 1.0399x over previous
//
#include <hip/hip_runtime.h>
#include <hip/hip_bf16.h>

typedef unsigned short u16;
typedef unsigned int u32;
typedef __attribute__((ext_vector_type(8))) short bf16x8;   // 8 bf16 (4 VGPRs)
typedef __attribute__((ext_vector_type(4))) float f32x4;

#define NL 2048
#define NH 16
// HD = 64; scale 1/8 and log2(e) folded into Q pre-scale

__device__ __forceinline__ float bf2f(u16 v) {
    union { float f; unsigned u; } x; x.u = ((unsigned)v) << 16; return x.f;
}
__device__ __forceinline__ u16 f2bf(float f) {
    union { __hip_bfloat16 h; u16 u; } x; x.h = __float2bfloat16(f); return x.u;
}
// round-half-up pack of two fp32 -> packed bf16 pair (finite inputs)
__device__ __forceinline__ u32 pk2(float a, float b) {
    union { float f; u32 u; } x, y; x.f = a; y.f = b;
    return ((x.u + 0x8000u) >> 16) | ((y.u + 0x8000u) & 0xffff0000u);
}
// truncating pack (1 VALU op): {hi16(hi), hi16(lo)} via v_perm_b32. Only for P:
// L is summed from the same packed values -> bias cancels in O = sum(pV)/sum(p).
__device__ __forceinline__ u32 pkt(float lo, float hi) {
    union { float f; u32 u; } x, y; x.f = lo; y.f = hi;
    return __builtin_amdgcn_perm(y.u, x.u, 0x07060302u);
}
#if __has_builtin(__builtin_amdgcn_exp2f)
#define EXP2F(x) __builtin_amdgcn_exp2f(x)
#else
#define EXP2F(x) __expf((x) * 0.69314718056f)
#endif

// async global->LDS, 16B per lane; LDS dest = wave-uniform base + lane*16
__device__ __forceinline__ void gload_lds16(const u16* g, u16* l) {
    __builtin_amdgcn_global_load_lds(
        (__attribute__((address_space(1))) void*)(g),
        (__attribute__((address_space(3))) void*)(l), 16, 0, 0);
}

// --------------------------------------- fp32 -> bf16 cast, all 3 inputs fused
__global__ __launch_bounds__(256) void cast_all_k(const float* __restrict__ x,
                                                  const float* __restrict__ wq,
                                                  const float* __restrict__ wp,
                                                  u16* __restrict__ xo,
                                                  u16* __restrict__ wqo,
                                                  u16* __restrict__ wpo) {
    int i = blockIdx.x * 256 + threadIdx.x;      // 0..3145727 (x4 elems)
    const float* src; u16* dst; int off;
    if (i < 2097152)      { src = x;  dst = xo;  off = i; }
    else if (i < 2883584) { src = wq; dst = wqo; off = i - 2097152; }
    else                  { src = wp; dst = wpo; off = i - 2883584; }
    float4 v = *(const float4*)&src[(size_t)off * 4];
    u16 tmp[4] = {f2bf(v.x), f2bf(v.y), f2bf(v.z), f2bf(v.w)};
    *(ushort4*)&dst[(size_t)off * 4] = *(ushort4*)tmp;
}

// ---------------------------------------------------------------- rope table
__global__ __launch_bounds__(256) void rope_table_k(float* __restrict__ cosT,
                                                    float* __restrict__ sinT) {
    int idx = blockIdx.x * 256 + threadIdx.x;    // L*32 = 65536
    int l = idx >> 5, i = idx & 31;
    float invf = exp2f(-(float)i * 0.41524101186092029f);  // log2(10000)/32
    float ang = (float)l * invf;
    cosT[idx] = cosf(ang);
    sinT[idx] = sinf(ang);
}

// ---------------------------------------------------- NT GEMM: C = A * B^T
// A [M][K] bf16, B [N][K] bf16, C [M][N] (bf16 or fp32). M%128, N%128, K%64 == 0.
// Staging via global_load_lds(16B); unpadded LDS with XOR chunk swizzle.
// (128^2 2-barrier structure; used for the proj GEMM where 256^2 would leave
// half the CUs idle: N=1024 -> only 128 blocks at 256^2.)
template <typename OutT>
__global__ __launch_bounds__(256) void gemm_bt(const u16* __restrict__ A,
                                               const u16* __restrict__ Bm,
                                               OutT* __restrict__ C,
                                               int M, int N, int K) {
    __shared__ u16 As[128][64];
    __shared__ u16 Bs[128][64];
    const int t = threadIdx.x;
    const int lane = t & 63, wave = t >> 6;
    const int quad = lane >> 4, lrow = lane & 15;
    const int wr = wave >> 1, wc = wave & 1;
    const size_t m0 = (size_t)blockIdx.y * 128, n0 = (size_t)blockIdx.x * 128;

    const int srow = wave * 32 + (lane >> 3);       // +j*8 covers 32 rows/wave
    const int scg  = (lane & 7) ^ (lane >> 3);      // swizzled global chunk

    f32x4 acc[4][4];
#pragma unroll
    for (int i = 0; i < 4; ++i)
#pragma unroll
        for (int j = 0; j < 4; ++j) acc[i][j] = (f32x4)0.0f;

    for (int k0 = 0; k0 < K; k0 += 64) {
#pragma unroll
        for (int j = 0; j < 4; ++j) {
            gload_lds16(&A[(m0 + srow + j * 8) * K + k0 + scg * 8],
                        &As[wave * 32 + j * 8][0]);
            gload_lds16(&Bm[(n0 + srow + j * 8) * K + k0 + scg * 8],
                        &Bs[wave * 32 + j * 8][0]);
        }
        __syncthreads();
#pragma unroll
        for (int ks = 0; ks < 2; ++ks) {
            bf16x8 av[4], bv[4];
#pragma unroll
            for (int i = 0; i < 4; ++i)
                av[i] = *(const bf16x8*)
                    &As[wr * 64 + i * 16 + lrow][(((ks << 2) | quad) ^ (lrow & 7)) << 3];
#pragma unroll
            for (int j = 0; j < 4; ++j)
                bv[j] = *(const bf16x8*)
                    &Bs[wc * 64 + j * 16 + lrow][(((ks << 2) | quad) ^ (lrow & 7)) << 3];
#pragma unroll
            for (int i = 0; i < 4; ++i)
#pragma unroll
                for (int j = 0; j < 4; ++j)
                    acc[i][j] = __builtin_amdgcn_mfma_f32_16x16x32_bf16(
                        av[i], bv[j], acc[i][j], 0, 0, 0);
        }
        __syncthreads();
    }
    // C/D layout: col = lane&15, row = quad*4 + r
#pragma unroll
    for (int i = 0; i < 4; ++i)
#pragma unroll
        for (int r = 0; r < 4; ++r) {
            size_t row = m0 + wr * 64 + i * 16 + quad * 4 + r;
#pragma unroll
            for (int j = 0; j < 4; ++j) {
                size_t col = n0 + wc * 64 + j * 16 + lrow;
                if constexpr (sizeof(OutT) == 4)
                    C[row * N + col] = acc[i][j][r];
                else
                    C[row * N + col] = f2bf(acc[i][j][r]);
            }
        }
}

// ------------------------------- 256^2 8-phase NT GEMM (T2+T3+T4+T5): C = A.B^T
// A [M][K] bf16, B [N][K] bf16, C [M][N] bf16. M%256==0, N%256==0, K%64==0.
// 8 waves / 512 thr; 128 KiB LDS double buffer (1 block/CU). Per K-tile: 4
// phases in Gray-code block-quadrant order (QM,QN)=(0,0),(0,1),(1,1),(1,0);
// all 8 waves compute one 128x128 C-quadrant per phase (wave = 64x32 piece),
// so each phase touches only A-half QM and B-half QN -> half-tile-granular
// prefetch with counted vmcnt (never 0 in main loop):
//   stage order for tile t+1: Ah0@ph1, Bh0@ph2, Bh1@ph3, Ah1@ph4 (2 loads/wave
//   each). vmcnt(4) before end-barrier of ph1/ph2/ph4 guarantees exactly the
//   halves the next phase(s) first-read, keeping 2-3 half-tiles in flight.
// Last K-tile peeled with vmcnt(2)/vmcnt(0) (no prefetch -> counts tighten).
__global__ __launch_bounds__(512, 2) void gemm256_bt(const u16* __restrict__ A,
                                                     const u16* __restrict__ Bm,
                                                     u16* __restrict__ C,
                                                     int M, int N, int K) {
    __shared__ __align__(16) char smem[131072];
    const int t = threadIdx.x;
    const int lane = t & 63, w = t >> 6;           // wave 0..7
    const int quad = lane >> 4, lq = lane & 15;
    const int wm = w >> 2, wn = w & 3;             // 2x4 waves per 128x128 quad
    const int rsub = lane >> 3;                    // 0..7
    const int scg  = (lane & 7) ^ rsub;            // swizzled global chunk
    const size_t m0 = (size_t)blockIdx.y * 256, n0 = (size_t)blockIdx.x * 256;
    const int NT = K >> 6;

#define ASB(buf) ((u16(*)[64])(smem + (size_t)(buf) * 65536))
#define BSB(buf) ((u16(*)[64])(smem + (size_t)(buf) * 65536 + 32768))
#define STAGE_A(buf, half, kt) { \
    const size_t kro_ = (size_t)(kt) * 64 + (size_t)(scg * 8); \
    gload_lds16(&A[(m0 + (half) * 128 + w * 16 + 0 + rsub) * (size_t)K + kro_], \
                &ASB(buf)[(half) * 128 + w * 16 + 0][0]); \
    gload_lds16(&A[(m0 + (half) * 128 + w * 16 + 8 + rsub) * (size_t)K + kro_], \
                &ASB(buf)[(half) * 128 + w * 16 + 8][0]); }
#define STAGE_B(buf, half, kt) { \
    const size_t kro_ = (size_t)(kt) * 64 + (size_t)(scg * 8); \
    gload_lds16(&Bm[(n0 + (half) * 128 + w * 16 + 0 + rsub) * (size_t)K + kro_], \
                &BSB(buf)[(half) * 128 + w * 16 + 0][0]); \
    gload_lds16(&Bm[(n0 + (half) * 128 + w * 16 + 8 + rsub) * (size_t)K + kro_], \
                &BSB(buf)[(half) * 128 + w * 16 + 8][0]); }
#define RD_A(dst, rowbase) { \
    _Pragma("unroll") for (int m_ = 0; m_ < 4; ++m_) \
    _Pragma("unroll") for (int ks_ = 0; ks_ < 2; ++ks_) \
        dst[m_][ks_] = *(const bf16x8*) \
            &Ac[(rowbase) + m_ * 16 + lq][(((ks_ << 2) | quad) ^ (lq & 7)) << 3]; }
#define RD_B(dst, rowbase) { \
    _Pragma("unroll") for (int n_ = 0; n_ < 2; ++n_) \
    _Pragma("unroll") for (int ks_ = 0; ks_ < 2; ++ks_) \
        dst[n_][ks_] = *(const bf16x8*) \
            &Bc[(rowbase) + n_ * 16 + lq][(((ks_ << 2) | quad) ^ (lq & 7)) << 3]; }
#define MM(QM, QN, bvv) { \
    _Pragma("unroll") for (int m_ = 0; m_ < 4; ++m_) \
    _Pragma("unroll") for (int n_ = 0; n_ < 2; ++n_) \
    _Pragma("unroll") for (int ks_ = 0; ks_ < 2; ++ks_) \
        acc[QM][QN][m_][n_] = __builtin_amdgcn_mfma_f32_16x16x32_bf16( \
            av[m_][ks_], bvv[n_][ks_], acc[QM][QN][m_][n_], 0, 0, 0); }

    f32x4 acc[2][2][4][2];
#pragma unroll
    for (int a = 0; a < 2; ++a)
#pragma unroll
        for (int b = 0; b < 2; ++b)
#pragma unroll
            for (int m = 0; m < 4; ++m)
#pragma unroll
                for (int n = 0; n < 2; ++n) acc[a][b][m][n] = (f32x4)0.0f;
    bf16x8 av[4][2], bv0[2][2], bv1[2][2];

    // prologue: stage all 4 halves of K-tile 0; wait for Ah0+Bh0 (oldest 4)
    STAGE_A(0, 0, 0); STAGE_B(0, 0, 0); STAGE_B(0, 1, 0); STAGE_A(0, 1, 0);
    asm volatile("s_waitcnt vmcnt(4)" ::: "memory");
    __builtin_amdgcn_s_barrier();

    for (int kt = 0; kt < NT - 1; ++kt) {
        const int cur = kt & 1, nxt = cur ^ 1;
        u16 (*Ac)[64] = ASB(cur);
        u16 (*Bc)[64] = BSB(cur);

        // phase 1: quadrant (0,0) — read Ah0 frags + Bh0 frags; stage Ah0'
        RD_A(av, wm * 64);
        RD_B(bv0, wn * 32);
        STAGE_A(nxt, 0, kt + 1);
        __builtin_amdgcn_s_barrier();
        __builtin_amdgcn_s_setprio(1);
        MM(0, 0, bv0);
        __builtin_amdgcn_s_setprio(0);
        asm volatile("s_waitcnt vmcnt(4)" ::: "memory");  // Bh1(t) landed
        __builtin_amdgcn_s_barrier();

        // phase 2: quadrant (0,1) — reuse av(Ah0); read Bh1 frags; stage Bh0'
        RD_B(bv1, 128 + wn * 32);
        STAGE_B(nxt, 0, kt + 1);
        __builtin_amdgcn_s_barrier();
        __builtin_amdgcn_s_setprio(1);
        MM(0, 1, bv1);
        __builtin_amdgcn_s_setprio(0);
        asm volatile("s_waitcnt vmcnt(4)" ::: "memory");  // Ah1(t) landed
        __builtin_amdgcn_s_barrier();

        // phase 3: quadrant (1,1) — read Ah1 frags; reuse bv1; stage Bh1'
        RD_A(av, 128 + wm * 64);
        STAGE_B(nxt, 1, kt + 1);
        __builtin_amdgcn_s_barrier();
        __builtin_amdgcn_s_setprio(1);
        MM(1, 1, bv1);
        __builtin_amdgcn_s_setprio(0);
        __builtin_amdgcn_s_barrier();                     // no vmcnt here

        // phase 4: quadrant (1,0) — reuse av(Ah1); re-read Bh0 frags; stage Ah1'
        RD_B(bv0, wn * 32);
        STAGE_A(nxt, 1, kt + 1);
        __builtin_amdgcn_s_barrier();
        __builtin_amdgcn_s_setprio(1);
        MM(1, 0, bv0);
        __builtin_amdgcn_s_setprio(0);
        asm volatile("s_waitcnt vmcnt(4)" ::: "memory");  // Ah0',Bh0' landed
        __builtin_amdgcn_s_barrier();
    }

    // peeled last K-tile: no prefetch -> counts tighten to 2 then 0
    {
        u16 (*Ac)[64] = ASB((NT - 1) & 1);
        u16 (*Bc)[64] = BSB((NT - 1) & 1);
        RD_A(av, wm * 64);
        RD_B(bv0, wn * 32);
        MM(0, 0, bv0);
        asm volatile("s_waitcnt vmcnt(2)" ::: "memory");  // Bh1 landed
        __builtin_amdgcn_s_barrier();
        RD_B(bv1, 128 + wn * 32);
        MM(0, 1, bv1);
        asm volatile("s_waitcnt vmcnt(0)" ::: "memory");  // Ah1 landed
        __builtin_amdgcn_s_barrier();
        RD_A(av, 128 + wm * 64);
        MM(1, 1, bv1);
        MM(1, 0, bv0);
    }

    // epilogue: C/D layout col = lane&15, row = quad*4 + r
#pragma unroll
    for (int QM = 0; QM < 2; ++QM)
#pragma unroll
        for (int QN = 0; QN < 2; ++QN)
#pragma unroll
            for (int m = 0; m < 4; ++m)
#pragma unroll
                for (int r = 0; r < 4; ++r) {
                    size_t row = m0 + QM * 128 + wm * 64 + m * 16 + quad * 4 + r;
#pragma unroll
                    for (int n = 0; n < 2; ++n) {
                        size_t col = n0 + QN * 128 + wn * 32 + n * 16 + lq;
                        C[row * N + col] = f2bf(acc[QM][QN][m][n][r]);
                    }
                }
#undef ASB
#undef BSB
#undef STAGE_A
#undef STAGE_B
#undef RD_A
#undef RD_B
#undef MM
}

// --------------- fused RoPE(q,k) + V-transpose: one pass over the qkv buffer
// grid (32 l-tiles, 64 bh), 256 thr. Q,K -> [BH][L][64] rope'd; V -> VT [BH*64][L].
__global__ __launch_bounds__(256) void rope_vt_k(const u16* __restrict__ qkv,
                                                 const float* __restrict__ cosT,
                                                 const float* __restrict__ sinT,
                                                 u16* __restrict__ Q,
                                                 u16* __restrict__ Ko,
                                                 u16* __restrict__ VT) {
    __shared__ u16 vtile[64][72];
    const int lt = blockIdx.x, bh = blockIdx.y;
    const int b = bh >> 4, h = bh & 15;
    const int l0 = lt * 64;
    const int t = threadIdx.x;
    const float SC = 0.180336879f;       // 1/8 * log2(e): exp2-ready logits
#pragma unroll
    for (int c = 0; c < 2; ++c) {
        int flat8 = c * 256 + t;         // 0..511
        int li = flat8 >> 3, dg = flat8 & 7;
        const u16* rowp = qkv + (size_t)(b * NL + l0 + li) * 3072 + h * 64 + dg * 8;
        uint4 qv = *(const uint4*)rowp;
        uint4 kv = *(const uint4*)(rowp + 1024);
        uint4 vv = *(const uint4*)(rowp + 2048);
        *(uint4*)&vtile[li][dg * 8] = vv;
        float4 cs = *(const float4*)&cosT[(l0 + li) * 32 + dg * 4];
        float4 sn = *(const float4*)&sinT[(l0 + li) * 32 + dg * 4];
        union { float f; u32 u; } w;
        float e0, o0, e1, o1, e2, o2, e3, o3;
        w.u = qv.x << 16; e0 = w.f; w.u = qv.x & 0xffff0000u; o0 = w.f;
        w.u = qv.y << 16; e1 = w.f; w.u = qv.y & 0xffff0000u; o1 = w.f;
        w.u = qv.z << 16; e2 = w.f; w.u = qv.z & 0xffff0000u; o2 = w.f;
        w.u = qv.w << 16; e3 = w.f; w.u = qv.w & 0xffff0000u; o3 = w.f;
        float c0 = cs.x * SC, c1 = cs.y * SC, c2 = cs.z * SC, c3 = cs.w * SC;
        float s0 = sn.x * SC, s1 = sn.y * SC, s2 = sn.z * SC, s3 = sn.w * SC;
        size_t ob = ((size_t)(b * NH + h) * NL + l0 + li) * 64;
        *(uint2*)&Q[ob + dg * 4] =
            make_uint2(pk2(e0 * c0 - o0 * s0, e1 * c1 - o1 * s1),
                       pk2(e2 * c2 - o2 * s2, e3 * c3 - o3 * s3));
        *(uint2*)&Q[ob + 32 + dg * 4] =
            make_uint2(pk2(e0 * s0 + o0 * c0, e1 * s1 + o1 * c1),
                       pk2(e2 * s2 + o2 * c2, e3 * s3 + o3 * c3));
        float f0, g0, f1, g1, f2, g2, f3, g3;
        w.u = kv.x << 16; f0 = w.f; w.u = kv.x & 0xffff0000u; g0 = w.f;
        w.u = kv.y << 16; f1 = w.f; w.u = kv.y & 0xffff0000u; g1 = w.f;
        w.u = kv.z << 16; f2 = w.f; w.u = kv.z & 0xffff0000u; g2 = w.f;
        w.u = kv.w << 16; f3 = w.f; w.u = kv.w & 0xffff0000u; g3 = w.f;
        *(uint2*)&Ko[ob + dg * 4] =
            make_uint2(pk2(f0 * cs.x - g0 * sn.x, f1 * cs.y - g1 * sn.y),
                       pk2(f2 * cs.z - g2 * sn.z, f3 * cs.w - g3 * sn.w));
        *(uint2*)&Ko[ob + 32 + dg * 4] =
            make_uint2(pk2(f0 * sn.x + g0 * cs.x, f1 * sn.y + g1 * cs.y),
                       pk2(f2 * sn.z + g2 * cs.z, f3 * sn.w + g3 * cs.w));
    }
    __syncthreads();
#pragma unroll
    for (int c = 0; c < 2; ++c) {
        int flat8 = c * 256 + t;
        int d = flat8 >> 3, lg = flat8 & 7;
        u16 tmp[8];
#pragma unroll
        for (int e = 0; e < 8; ++e) tmp[e] = vtile[lg * 8 + e][d];
        *(uint4*)&VT[((size_t)(bh * 64 + d)) * NL + l0 + lg * 8] = *(uint4*)tmp;
    }
}

// --------------------------------------------- flash attention (MFMA)
// 256 q per block, 8 waves x 32 q (two 16-col halves qh=0,1 sharing every
// K/V fragment read -> 2x LDS arithmetic intensity). S^T = K.Q^T (query in
// C/D column). Single barrier per chunk with K/V double-buffer prefetch.
// No online max (logits bounded); p = exp2(s), trunc-packed via v_perm,
// row-sum L via all-ones-A MFMA, single divide at the end.
__global__ __launch_bounds__(512, 4) void attn_k(const u16* __restrict__ Q,
                                                 const u16* __restrict__ Kg,
                                                 const u16* __restrict__ VT,
                                                 u16* __restrict__ Og) {
    __shared__ __align__(16) char smem[65536];
    u16 (*KsB)[64][64] = (u16(*)[64][64])(smem);           // 2 bufs @0, 8192
    u16 (*VsB)[64][64] = (u16(*)[64][64])(smem + 16384);   // 2 bufs @16384, 24576
    u16* PsBase = (u16*)(smem + 32768);                    // 8 waves x 4096 B
    const int t = threadIdx.x;
    const int lane = t & 63, wave = t >> 6;                // wave 0..7
    const int quad = lane >> 4, lq = lane & 15;
    u16* PsW = PsBase + wave * 2048;                       // [32 q][64 k] swz

    const int qt = blockIdx.x, bh = blockIdx.y;
    const int q0 = qt * 256;
    const size_t qkbase = (size_t)bh * NL * 64;

    const int rsub = lane >> 3;                            // 0..7
    const int scg  = (lane & 7) ^ rsub;                    // swizzled global chunk

    // preloop: stage Q (256x64, through Ps region) + prefetch chunk 0
    u16 (*Qtmp)[64] = (u16(*)[64])(smem + 32768);
#pragma unroll
    for (int j = 0; j < 4; ++j)
        gload_lds16(&Q[qkbase + (size_t)(q0 + wave * 32 + j * 8 + rsub) * 64 + scg * 8],
                    &Qtmp[wave * 32 + j * 8][0]);
    const u16* kptr = Kg + qkbase + (size_t)(wave * 8 + rsub) * 64 + scg * 8;
    const u16* vptr = VT + qkbase + (size_t)(wave * 8 + rsub) * NL + scg * 8;
    gload_lds16(kptr, &KsB[0][wave * 8][0]);
    gload_lds16(vptr, &VsB[0][wave * 8][0]);
    kptr += 64 * 64;
    vptr += 64;
    __syncthreads();                      // Q + chunk0 resident
    bf16x8 bq[2][2];                      // Q frags: invariant across chunks
#pragma unroll
    for (int qh = 0; qh < 2; ++qh)
#pragma unroll
        for (int ks = 0; ks < 2; ++ks)
            bq[qh][ks] = *(const bf16x8*)
                &Qtmp[wave * 32 + qh * 16 + lq][(((ks << 2) | quad) ^ (lq & 7)) << 3];

    const bf16x8 ones = (bf16x8)(short)16256;              // bf16 1.0 splat
    f32x4 ot[2][4];                       // O^T rows d = mt*16+quad*4+r
#pragma unroll
    for (int qh = 0; qh < 2; ++qh)
#pragma unroll
        for (int mt = 0; mt < 4; ++mt) ot[qh][mt] = (f32x4)0.0f;
    f32x4 lacc[2] = {(f32x4)0.0f, (f32x4)0.0f};

    for (int kc = 0; kc < NL / 64; ++kc) {
        __syncthreads();                  // prev chunk consumed; prefetch landed
        if (kc < NL / 64 - 1) {
            gload_lds16(kptr, &KsB[(kc + 1) & 1][wave * 8][0]);
            gload_lds16(vptr, &VsB[(kc + 1) & 1][wave * 8][0]);
            kptr += 64 * 64;
            vptr += 64;
        }
        const int cur = kc & 1;

        // S^T = K_chunk (64k x 64d) . Q^T (64d x 32q); K frag feeds both halves
        f32x4 st[2][4];
#pragma unroll
        for (int qh = 0; qh < 2; ++qh)
#pragma unroll
            for (int mt = 0; mt < 4; ++mt) st[qh][mt] = (f32x4)0.0f;
#pragma unroll
        for (int ks = 0; ks < 2; ++ks)
#pragma unroll
            for (int mt = 0; mt < 4; ++mt) {
                bf16x8 ak = *(const bf16x8*)
                    &KsB[cur][mt * 16 + lq][(((ks << 2) | quad) ^ (lq & 7)) << 3];
                st[0][mt] = __builtin_amdgcn_mfma_f32_16x16x32_bf16(ak, bq[0][ks], st[0][mt], 0, 0, 0);
                st[1][mt] = __builtin_amdgcn_mfma_f32_16x16x32_bf16(ak, bq[1][ks], st[1][mt], 0, 0, 0);
            }

        // p = exp2(s); 1-op trunc pack; swizzled uint2 stores to Ps
#pragma unroll
        for (int qh = 0; qh < 2; ++qh)
#pragma unroll
            for (int mt = 0; mt < 4; ++mt) {
                int pblk = (mt * 2 + (quad >> 1)) ^ (lq & 7);
                *(uint2*)&PsW[(qh * 16 + lq) * 64 + pblk * 8 + (quad & 1) * 4] =
                    make_uint2(pkt(EXP2F(st[qh][mt][0]), EXP2F(st[qh][mt][1])),
                               pkt(EXP2F(st[qh][mt][2]), EXP2F(st[qh][mt][3])));
            }
        __builtin_amdgcn_s_waitcnt(0xc07f);  // lgkmcnt(0): intra-wave LDS RAW

        // O^T += V^T_chunk . P^T ; L += ones . P^T; V frag feeds both halves
#pragma unroll
        for (int ks = 0; ks < 2; ++ks) {
            const int sw = (((ks << 2) | quad) ^ (lq & 7)) * 8;
            bf16x8 bp0 = *(const bf16x8*)&PsW[lq * 64 + sw];
            bf16x8 bp1 = *(const bf16x8*)&PsW[(16 + lq) * 64 + sw];
            lacc[0] = __builtin_amdgcn_mfma_f32_16x16x32_bf16(ones, bp0, lacc[0], 0, 0, 0);
            lacc[1] = __builtin_amdgcn_mfma_f32_16x16x32_bf16(ones, bp1, lacc[1], 0, 0, 0);
#pragma unroll
            for (int mt = 0; mt < 4; ++mt) {
                bf16x8 av = *(const bf16x8*)
                    &VsB[cur][mt * 16 + lq][(((ks << 2) | quad) ^ (lq & 7)) << 3];
                ot[0][mt] = __builtin_amdgcn_mfma_f32_16x16x32_bf16(av, bp0, ot[0][mt], 0, 0, 0);
                ot[1][mt] = __builtin_amdgcn_mfma_f32_16x16x32_bf16(av, bp1, ot[1][mt], 0, 0, 0);
            }
        }
    }

    // epilogue: transpose O^T through LDS, one 16-q half at a time
    __syncthreads();
    float* OT_ls = (float*)(smem + wave * 4352);     // [64 d][17] floats, per wave
    float* Ls_ls = (float*)(smem + 34816);           // 8 waves x 16 q
    const int b = bh >> 4, h = bh & 15;
    const int qq = lane >> 2, dblk = lane & 3;       // 16 rows x 4 d-blocks
#pragma unroll
    for (int qh = 0; qh < 2; ++qh) {
#pragma unroll
        for (int mt = 0; mt < 4; ++mt)
#pragma unroll
            for (int r = 0; r < 4; ++r)
                OT_ls[(mt * 16 + quad * 4 + r) * 17 + lq] = ot[qh][mt][r];
        if (quad == 0) Ls_ls[wave * 16 + lq] = lacc[qh][0];
        __builtin_amdgcn_s_waitcnt(0xc07f);          // intra-wave LDS RAW

        float rls = 1.0f / Ls_ls[wave * 16 + qq];
        u16 tmp[16];
#pragma unroll
        for (int e = 0; e < 16; ++e)
            tmp[e] = f2bf(OT_ls[(dblk * 16 + e) * 17 + qq] * rls);
        size_t orow = (size_t)b * NL + q0 + wave * 32 + qh * 16 + qq;
        size_t obase = orow * 1024 + h * 64 + dblk * 16;
        *(uint4*)&Og[obase] = *(uint4*)&tmp[0];
        *(uint4*)&Og[obase + 8] = *(uint4*)&tmp[8];
    }
}

// ----------------------------------------------------------------- launch
extern "C" void kernel_launch(void* const* d_in, const int* in_sizes, int n_in,
                              void* d_out, int out_size, void* d_ws, size_t ws_size,
                              hipStream_t stream) {
    const float* x     = (const float*)d_in[0];   // [8192][1024] fp32
    const float* Wqkv  = (const float*)d_in[1];   // [3072][1024] fp32
    const float* Wproj = (const float*)d_in[2];   // [1024][1024] fp32
    float* out = (float*)d_out;                   // [8192][1024] fp32

    char* ws = (char*)d_ws;
    u16* qkv     = (u16*)ws;                      // 50,331,648 B
    u16* attnout = (u16*)ws;                      // reuses qkv region (dead by then)
    u16* Qw      = (u16*)(ws + 50331648);         // 16,777,216 B
    u16* Kw      = (u16*)(ws + 67108864);         // 16,777,216 B
    u16* VTw     = (u16*)(ws + 83886080);         // 16,777,216 B
    float* cosT  = (float*)(ws + 100663296);      //    262,144 B
    float* sinT  = (float*)(ws + 100925440);      //    262,144 B
    u16* x_bf    = (u16*)(ws + 101187584);        // 16,777,216 B
    u16* Wqkv_bf = (u16*)(ws + 117964800);        //  6,291,456 B
    u16* Wproj_bf= (u16*)(ws + 124256256);        //  2,097,152 B  (total ~126.4 MB)

    rope_table_k<<<256, 256, 0, stream>>>(cosT, sinT);
    cast_all_k<<<12288, 256, 0, stream>>>(x, Wqkv, Wproj, x_bf, Wqkv_bf, Wproj_bf);
    gemm256_bt<<<dim3(12, 32), 512, 0, stream>>>(x_bf, Wqkv_bf, qkv, 8192, 3072, 1024);
    rope_vt_k<<<dim3(32, 64), 256, 0, stream>>>(qkv, cosT, sinT, Qw, Kw, VTw);
    attn_k<<<dim3(8, 64), 512, 0, stream>>>(Qw, Kw, VTw, attnout);
    gemm_bt<float><<<dim3(8, 64), 256, 0, stream>>>(attnout, Wproj_bf, out, 8192, 1024, 1024);
}

// Round 4
// 263.665 us; speedup vs baseline: 1.0481x; 1.0079x over previous
//
#include <hip/hip_runtime.h>
#include <hip/hip_bf16.h>

typedef unsigned short u16;
typedef unsigned int u32;
typedef __attribute__((ext_vector_type(8))) short bf16x8;   // 8 bf16 (4 VGPRs)
typedef __attribute__((ext_vector_type(4))) float f32x4;
typedef __attribute__((ext_vector_type(2))) unsigned int u32x2;

#define NL 2048
#define NH 16
// HD = 64; scale 1/8 and log2(e) folded into Q pre-scale

__device__ __forceinline__ float bf2f(u16 v) {
    union { float f; unsigned u; } x; x.u = ((unsigned)v) << 16; return x.f;
}
__device__ __forceinline__ u16 f2bf(float f) {
    union { __hip_bfloat16 h; u16 u; } x; x.h = __float2bfloat16(f); return x.u;
}
// round-half-up pack of two fp32 -> packed bf16 pair (finite inputs)
__device__ __forceinline__ u32 pk2(float a, float b) {
    union { float f; u32 u; } x, y; x.f = a; y.f = b;
    return ((x.u + 0x8000u) >> 16) | ((y.u + 0x8000u) & 0xffff0000u);
}
// truncating pack (1 VALU op): {hi16(hi), hi16(lo)} via v_perm_b32. Only for P:
// L is summed from the same packed values -> bias cancels in O = sum(pV)/sum(p).
__device__ __forceinline__ u32 pkt(float lo, float hi) {
    union { float f; u32 u; } x, y; x.f = lo; y.f = hi;
    return __builtin_amdgcn_perm(y.u, x.u, 0x07060302u);
}
#if __has_builtin(__builtin_amdgcn_exp2f)
#define EXP2F(x) __builtin_amdgcn_exp2f(x)
#else
#define EXP2F(x) __expf((x) * 0.69314718056f)
#endif

// quad exchange for the P^T->B-operand transpose: two permlane swaps.
// After: first = {A.q0, A.q2, B.q0, B.q2}, second = {A.q1, A.q3, B.q1, B.q3}.
// Builtins preferred: compiler inserts the VALU->permlane hazard wait states
// (raw inline asm without s_nop guards reads stale VGPRs -> round-3 failure).
__device__ __forceinline__ void quad_xchg(u32& a, u32& b) {
#if __has_builtin(__builtin_amdgcn_permlane32_swap) && __has_builtin(__builtin_amdgcn_permlane16_swap)
    u32x2 r0 = __builtin_amdgcn_permlane32_swap(a, b, false, false);
    u32x2 r1 = __builtin_amdgcn_permlane16_swap(r0.x, r0.y, false, false);
    a = r1.x; b = r1.y;
#else
    asm volatile("s_nop 1\n\t"
                 "v_permlane32_swap_b32 %0, %1\n\t"
                 "s_nop 1\n\t"
                 "v_permlane16_swap_b32 %0, %1\n\t"
                 "s_nop 1"
                 : "+v"(a), "+v"(b));
#endif
}

// async global->LDS, 16B per lane; LDS dest = wave-uniform base + lane*16
__device__ __forceinline__ void gload_lds16(const u16* g, u16* l) {
    __builtin_amdgcn_global_load_lds(
        (__attribute__((address_space(1))) void*)(g),
        (__attribute__((address_space(3))) void*)(l), 16, 0, 0);
}

// --------------------------------------- fp32 -> bf16 cast, all 3 inputs fused
__global__ __launch_bounds__(256) void cast_all_k(const float* __restrict__ x,
                                                  const float* __restrict__ wq,
                                                  const float* __restrict__ wp,
                                                  u16* __restrict__ xo,
                                                  u16* __restrict__ wqo,
                                                  u16* __restrict__ wpo) {
    int i = blockIdx.x * 256 + threadIdx.x;      // 0..3145727 (x4 elems)
    const float* src; u16* dst; int off;
    if (i < 2097152)      { src = x;  dst = xo;  off = i; }
    else if (i < 2883584) { src = wq; dst = wqo; off = i - 2097152; }
    else                  { src = wp; dst = wpo; off = i - 2883584; }
    float4 v = *(const float4*)&src[(size_t)off * 4];
    u16 tmp[4] = {f2bf(v.x), f2bf(v.y), f2bf(v.z), f2bf(v.w)};
    *(ushort4*)&dst[(size_t)off * 4] = *(ushort4*)tmp;
}

// ---------------------------------------------------------------- rope table
__global__ __launch_bounds__(256) void rope_table_k(float* __restrict__ cosT,
                                                    float* __restrict__ sinT) {
    int idx = blockIdx.x * 256 + threadIdx.x;    // L*32 = 65536
    int l = idx >> 5, i = idx & 31;
    float invf = exp2f(-(float)i * 0.41524101186092029f);  // log2(10000)/32
    float ang = (float)l * invf;
    cosT[idx] = cosf(ang);
    sinT[idx] = sinf(ang);
}

// ---------------------------------------------------- NT GEMM: C = A * B^T
// A [M][K] bf16, B [N][K] bf16, C [M][N] (bf16 or fp32). M%128, N%128, K%64 == 0.
// Staging via global_load_lds(16B); unpadded LDS with XOR chunk swizzle.
// (128^2 2-barrier structure; used for the proj GEMM where 256^2 would leave
// half the CUs idle: N=1024 -> only 128 blocks at 256^2.)
template <typename OutT>
__global__ __launch_bounds__(256) void gemm_bt(const u16* __restrict__ A,
                                               const u16* __restrict__ Bm,
                                               OutT* __restrict__ C,
                                               int M, int N, int K) {
    __shared__ u16 As[128][64];
    __shared__ u16 Bs[128][64];
    const int t = threadIdx.x;
    const int lane = t & 63, wave = t >> 6;
    const int quad = lane >> 4, lrow = lane & 15;
    const int wr = wave >> 1, wc = wave & 1;
    const size_t m0 = (size_t)blockIdx.y * 128, n0 = (size_t)blockIdx.x * 128;

    const int srow = wave * 32 + (lane >> 3);       // +j*8 covers 32 rows/wave
    const int scg  = (lane & 7) ^ (lane >> 3);      // swizzled global chunk

    f32x4 acc[4][4];
#pragma unroll
    for (int i = 0; i < 4; ++i)
#pragma unroll
        for (int j = 0; j < 4; ++j) acc[i][j] = (f32x4)0.0f;

    for (int k0 = 0; k0 < K; k0 += 64) {
#pragma unroll
        for (int j = 0; j < 4; ++j) {
            gload_lds16(&A[(m0 + srow + j * 8) * K + k0 + scg * 8],
                        &As[wave * 32 + j * 8][0]);
            gload_lds16(&Bm[(n0 + srow + j * 8) * K + k0 + scg * 8],
                        &Bs[wave * 32 + j * 8][0]);
        }
        __syncthreads();
#pragma unroll
        for (int ks = 0; ks < 2; ++ks) {
            bf16x8 av[4], bv[4];
#pragma unroll
            for (int i = 0; i < 4; ++i)
                av[i] = *(const bf16x8*)
                    &As[wr * 64 + i * 16 + lrow][(((ks << 2) | quad) ^ (lrow & 7)) << 3];
#pragma unroll
            for (int j = 0; j < 4; ++j)
                bv[j] = *(const bf16x8*)
                    &Bs[wc * 64 + j * 16 + lrow][(((ks << 2) | quad) ^ (lrow & 7)) << 3];
#pragma unroll
            for (int i = 0; i < 4; ++i)
#pragma unroll
                for (int j = 0; j < 4; ++j)
                    acc[i][j] = __builtin_amdgcn_mfma_f32_16x16x32_bf16(
                        av[i], bv[j], acc[i][j], 0, 0, 0);
        }
        __syncthreads();
    }
    // C/D layout: col = lane&15, row = quad*4 + r
#pragma unroll
    for (int i = 0; i < 4; ++i)
#pragma unroll
        for (int r = 0; r < 4; ++r) {
            size_t row = m0 + wr * 64 + i * 16 + quad * 4 + r;
#pragma unroll
            for (int j = 0; j < 4; ++j) {
                size_t col = n0 + wc * 64 + j * 16 + lrow;
                if constexpr (sizeof(OutT) == 4)
                    C[row * N + col] = acc[i][j][r];
                else
                    C[row * N + col] = f2bf(acc[i][j][r]);
            }
        }
}

// ------------------------------- 256^2 8-phase NT GEMM (T2+T3+T4+T5): C = A.B^T
// A [M][K] bf16, B [N][K] bf16, C [M][N] bf16. M%256==0, N%256==0, K%64==0.
// 8 waves / 512 thr; 128 KiB LDS double buffer (1 block/CU). Per K-tile: 4
// phases in Gray-code block-quadrant order (QM,QN)=(0,0),(0,1),(1,1),(1,0);
// all 8 waves compute one 128x128 C-quadrant per phase (wave = 64x32 piece),
// so each phase touches only A-half QM and B-half QN -> half-tile-granular
// prefetch with counted vmcnt (never 0 in main loop):
//   stage order for tile t+1: Ah0@ph1, Bh0@ph2, Bh1@ph3, Ah1@ph4 (2 loads/wave
//   each). vmcnt(4) before end-barrier of ph1/ph2/ph4 guarantees exactly the
//   halves the next phase(s) first-read, keeping 2-3 half-tiles in flight.
// Last K-tile peeled with vmcnt(2)/vmcnt(0) (no prefetch -> counts tighten).
__global__ __launch_bounds__(512, 2) void gemm256_bt(const u16* __restrict__ A,
                                                     const u16* __restrict__ Bm,
                                                     u16* __restrict__ C,
                                                     int M, int N, int K) {
    __shared__ __align__(16) char smem[131072];
    const int t = threadIdx.x;
    const int lane = t & 63, w = t >> 6;           // wave 0..7
    const int quad = lane >> 4, lq = lane & 15;
    const int wm = w >> 2, wn = w & 3;             // 2x4 waves per 128x128 quad
    const int rsub = lane >> 3;                    // 0..7
    const int scg  = (lane & 7) ^ rsub;            // swizzled global chunk
    const size_t m0 = (size_t)blockIdx.y * 256, n0 = (size_t)blockIdx.x * 256;
    const int NT = K >> 6;

#define ASB(buf) ((u16(*)[64])(smem + (size_t)(buf) * 65536))
#define BSB(buf) ((u16(*)[64])(smem + (size_t)(buf) * 65536 + 32768))
#define STAGE_A(buf, half, kt) { \
    const size_t kro_ = (size_t)(kt) * 64 + (size_t)(scg * 8); \
    gload_lds16(&A[(m0 + (half) * 128 + w * 16 + 0 + rsub) * (size_t)K + kro_], \
                &ASB(buf)[(half) * 128 + w * 16 + 0][0]); \
    gload_lds16(&A[(m0 + (half) * 128 + w * 16 + 8 + rsub) * (size_t)K + kro_], \
                &ASB(buf)[(half) * 128 + w * 16 + 8][0]); }
#define STAGE_B(buf, half, kt) { \
    const size_t kro_ = (size_t)(kt) * 64 + (size_t)(scg * 8); \
    gload_lds16(&Bm[(n0 + (half) * 128 + w * 16 + 0 + rsub) * (size_t)K + kro_], \
                &BSB(buf)[(half) * 128 + w * 16 + 0][0]); \
    gload_lds16(&Bm[(n0 + (half) * 128 + w * 16 + 8 + rsub) * (size_t)K + kro_], \
                &BSB(buf)[(half) * 128 + w * 16 + 8][0]); }
#define RD_A(dst, rowbase) { \
    _Pragma("unroll") for (int m_ = 0; m_ < 4; ++m_) \
    _Pragma("unroll") for (int ks_ = 0; ks_ < 2; ++ks_) \
        dst[m_][ks_] = *(const bf16x8*) \
            &Ac[(rowbase) + m_ * 16 + lq][(((ks_ << 2) | quad) ^ (lq & 7)) << 3]; }
#define RD_B(dst, rowbase) { \
    _Pragma("unroll") for (int n_ = 0; n_ < 2; ++n_) \
    _Pragma("unroll") for (int ks_ = 0; ks_ < 2; ++ks_) \
        dst[n_][ks_] = *(const bf16x8*) \
            &Bc[(rowbase) + n_ * 16 + lq][(((ks_ << 2) | quad) ^ (lq & 7)) << 3]; }
#define MM(QM, QN, bvv) { \
    _Pragma("unroll") for (int m_ = 0; m_ < 4; ++m_) \
    _Pragma("unroll") for (int n_ = 0; n_ < 2; ++n_) \
    _Pragma("unroll") for (int ks_ = 0; ks_ < 2; ++ks_) \
        acc[QM][QN][m_][n_] = __builtin_amdgcn_mfma_f32_16x16x32_bf16( \
            av[m_][ks_], bvv[n_][ks_], acc[QM][QN][m_][n_], 0, 0, 0); }

    f32x4 acc[2][2][4][2];
#pragma unroll
    for (int a = 0; a < 2; ++a)
#pragma unroll
        for (int b = 0; b < 2; ++b)
#pragma unroll
            for (int m = 0; m < 4; ++m)
#pragma unroll
                for (int n = 0; n < 2; ++n) acc[a][b][m][n] = (f32x4)0.0f;
    bf16x8 av[4][2], bv0[2][2], bv1[2][2];

    // prologue: stage all 4 halves of K-tile 0; wait for Ah0+Bh0 (oldest 4)
    STAGE_A(0, 0, 0); STAGE_B(0, 0, 0); STAGE_B(0, 1, 0); STAGE_A(0, 1, 0);
    asm volatile("s_waitcnt vmcnt(4)" ::: "memory");
    __builtin_amdgcn_s_barrier();

    for (int kt = 0; kt < NT - 1; ++kt) {
        const int cur = kt & 1, nxt = cur ^ 1;
        u16 (*Ac)[64] = ASB(cur);
        u16 (*Bc)[64] = BSB(cur);

        // phase 1: quadrant (0,0) — read Ah0 frags + Bh0 frags; stage Ah0'
        RD_A(av, wm * 64);
        RD_B(bv0, wn * 32);
        STAGE_A(nxt, 0, kt + 1);
        __builtin_amdgcn_s_barrier();
        __builtin_amdgcn_s_setprio(1);
        MM(0, 0, bv0);
        __builtin_amdgcn_s_setprio(0);
        asm volatile("s_waitcnt vmcnt(4)" ::: "memory");  // Bh1(t) landed
        __builtin_amdgcn_s_barrier();

        // phase 2: quadrant (0,1) — reuse av(Ah0); read Bh1 frags; stage Bh0'
        RD_B(bv1, 128 + wn * 32);
        STAGE_B(nxt, 0, kt + 1);
        __builtin_amdgcn_s_barrier();
        __builtin_amdgcn_s_setprio(1);
        MM(0, 1, bv1);
        __builtin_amdgcn_s_setprio(0);
        asm volatile("s_waitcnt vmcnt(4)" ::: "memory");  // Ah1(t) landed
        __builtin_amdgcn_s_barrier();

        // phase 3: quadrant (1,1) — read Ah1 frags; reuse bv1; stage Bh1'
        RD_A(av, 128 + wm * 64);
        STAGE_B(nxt, 1, kt + 1);
        __builtin_amdgcn_s_barrier();
        __builtin_amdgcn_s_setprio(1);
        MM(1, 1, bv1);
        __builtin_amdgcn_s_setprio(0);
        __builtin_amdgcn_s_barrier();                     // no vmcnt here

        // phase 4: quadrant (1,0) — reuse av(Ah1); re-read Bh0 frags; stage Ah1'
        RD_B(bv0, wn * 32);
        STAGE_A(nxt, 1, kt + 1);
        __builtin_amdgcn_s_barrier();
        __builtin_amdgcn_s_setprio(1);
        MM(1, 0, bv0);
        __builtin_amdgcn_s_setprio(0);
        asm volatile("s_waitcnt vmcnt(4)" ::: "memory");  // Ah0',Bh0' landed
        __builtin_amdgcn_s_barrier();
    }

    // peeled last K-tile: no prefetch -> counts tighten to 2 then 0
    {
        u16 (*Ac)[64] = ASB((NT - 1) & 1);
        u16 (*Bc)[64] = BSB((NT - 1) & 1);
        RD_A(av, wm * 64);
        RD_B(bv0, wn * 32);
        MM(0, 0, bv0);
        asm volatile("s_waitcnt vmcnt(2)" ::: "memory");  // Bh1 landed
        __builtin_amdgcn_s_barrier();
        RD_B(bv1, 128 + wn * 32);
        MM(0, 1, bv1);
        asm volatile("s_waitcnt vmcnt(0)" ::: "memory");  // Ah1 landed
        __builtin_amdgcn_s_barrier();
        RD_A(av, 128 + wm * 64);
        MM(1, 1, bv1);
        MM(1, 0, bv0);
    }

    // epilogue: C/D layout col = lane&15, row = quad*4 + r
#pragma unroll
    for (int QM = 0; QM < 2; ++QM)
#pragma unroll
        for (int QN = 0; QN < 2; ++QN)
#pragma unroll
            for (int m = 0; m < 4; ++m)
#pragma unroll
                for (int r = 0; r < 4; ++r) {
                    size_t row = m0 + QM * 128 + wm * 64 + m * 16 + quad * 4 + r;
#pragma unroll
                    for (int n = 0; n < 2; ++n) {
                        size_t col = n0 + QN * 128 + wn * 32 + n * 16 + lq;
                        C[row * N + col] = f2bf(acc[QM][QN][m][n][r]);
                    }
                }
#undef ASB
#undef BSB
#undef STAGE_A
#undef STAGE_B
#undef RD_A
#undef RD_B
#undef MM
}

// --------------- fused RoPE(q,k) + V-transpose: one pass over the qkv buffer
// grid (32 l-tiles, 64 bh), 256 thr. Q,K -> [BH][L][64] rope'd; V -> VT [BH*64][L].
__global__ __launch_bounds__(256) void rope_vt_k(const u16* __restrict__ qkv,
                                                 const float* __restrict__ cosT,
                                                 const float* __restrict__ sinT,
                                                 u16* __restrict__ Q,
                                                 u16* __restrict__ Ko,
                                                 u16* __restrict__ VT) {
    __shared__ u16 vtile[64][72];
    const int lt = blockIdx.x, bh = blockIdx.y;
    const int b = bh >> 4, h = bh & 15;
    const int l0 = lt * 64;
    const int t = threadIdx.x;
    const float SC = 0.180336879f;       // 1/8 * log2(e): exp2-ready logits
#pragma unroll
    for (int c = 0; c < 2; ++c) {
        int flat8 = c * 256 + t;         // 0..511
        int li = flat8 >> 3, dg = flat8 & 7;
        const u16* rowp = qkv + (size_t)(b * NL + l0 + li) * 3072 + h * 64 + dg * 8;
        uint4 qv = *(const uint4*)rowp;
        uint4 kv = *(const uint4*)(rowp + 1024);
        uint4 vv = *(const uint4*)(rowp + 2048);
        *(uint4*)&vtile[li][dg * 8] = vv;
        float4 cs = *(const float4*)&cosT[(l0 + li) * 32 + dg * 4];
        float4 sn = *(const float4*)&sinT[(l0 + li) * 32 + dg * 4];
        union { float f; u32 u; } w;
        float e0, o0, e1, o1, e2, o2, e3, o3;
        w.u = qv.x << 16; e0 = w.f; w.u = qv.x & 0xffff0000u; o0 = w.f;
        w.u = qv.y << 16; e1 = w.f; w.u = qv.y & 0xffff0000u; o1 = w.f;
        w.u = qv.z << 16; e2 = w.f; w.u = qv.z & 0xffff0000u; o2 = w.f;
        w.u = qv.w << 16; e3 = w.f; w.u = qv.w & 0xffff0000u; o3 = w.f;
        float c0 = cs.x * SC, c1 = cs.y * SC, c2 = cs.z * SC, c3 = cs.w * SC;
        float s0 = sn.x * SC, s1 = sn.y * SC, s2 = sn.z * SC, s3 = sn.w * SC;
        size_t ob = ((size_t)(b * NH + h) * NL + l0 + li) * 64;
        *(uint2*)&Q[ob + dg * 4] =
            make_uint2(pk2(e0 * c0 - o0 * s0, e1 * c1 - o1 * s1),
                       pk2(e2 * c2 - o2 * s2, e3 * c3 - o3 * s3));
        *(uint2*)&Q[ob + 32 + dg * 4] =
            make_uint2(pk2(e0 * s0 + o0 * c0, e1 * s1 + o1 * c1),
                       pk2(e2 * s2 + o2 * c2, e3 * s3 + o3 * c3));
        float f0, g0, f1, g1, f2, g2, f3, g3;
        w.u = kv.x << 16; f0 = w.f; w.u = kv.x & 0xffff0000u; g0 = w.f;
        w.u = kv.y << 16; f1 = w.f; w.u = kv.y & 0xffff0000u; g1 = w.f;
        w.u = kv.z << 16; f2 = w.f; w.u = kv.z & 0xffff0000u; g2 = w.f;
        w.u = kv.w << 16; f3 = w.f; w.u = kv.w & 0xffff0000u; g3 = w.f;
        *(uint2*)&Ko[ob + dg * 4] =
            make_uint2(pk2(f0 * cs.x - g0 * sn.x, f1 * cs.y - g1 * sn.y),
                       pk2(f2 * cs.z - g2 * sn.z, f3 * cs.w - g3 * sn.w));
        *(uint2*)&Ko[ob + 32 + dg * 4] =
            make_uint2(pk2(f0 * sn.x + g0 * cs.x, f1 * sn.y + g1 * cs.y),
                       pk2(f2 * sn.z + g2 * cs.z, f3 * sn.w + g3 * cs.w));
    }
    __syncthreads();
#pragma unroll
    for (int c = 0; c < 2; ++c) {
        int flat8 = c * 256 + t;
        int d = flat8 >> 3, lg = flat8 & 7;
        u16 tmp[8];
#pragma unroll
        for (int e = 0; e < 8; ++e) tmp[e] = vtile[lg * 8 + e][d];
        *(uint4*)&VT[((size_t)(bh * 64 + d)) * NL + l0 + lg * 8] = *(uint4*)tmp;
    }
}

// --------------------------------------------- flash attention (MFMA)
// 256 q per block, 8 waves x 32 q (two 16-col halves qh=0,1 sharing every
// K/V fragment read -> 2x LDS arithmetic intensity). S^T = K.Q^T (query in
// C/D column). Single barrier per chunk with K/V double-buffer prefetch.
// No online max (logits bounded); p = exp2(s), trunc-packed via v_perm.
// P^T is transposed IN REGISTERS (permlane32/16_swap quad exchange, via
// builtins for hazard-safe codegen): no P LDS round-trip, no per-chunk
// lgkmcnt(0) stop -> 16 (not 28) DS ops/chunk. Row-sum L via all-ones-A
// MFMA, single divide at the end.
// XCD-aware block remap: all 8 q-tiles of a bh land on one XCD (K/V L2 reuse).
__global__ __launch_bounds__(512, 4) void attn_k(const u16* __restrict__ Q,
                                                 const u16* __restrict__ Kg,
                                                 const u16* __restrict__ VT,
                                                 u16* __restrict__ Og) {
    __shared__ __align__(16) char smem[65536];
    u16 (*KsB)[64][64] = (u16(*)[64][64])(smem);           // 2 bufs @0, 8192
    u16 (*VsB)[64][64] = (u16(*)[64][64])(smem + 16384);   // 2 bufs @16384, 24576
    const int t = threadIdx.x;
    const int lane = t & 63, wave = t >> 6;                // wave 0..7
    const int quad = lane >> 4, lq = lane & 15;

    // bijective XCD remap: flat bits [2:0]->bh lo (XCD), [5:3]->qt, [8:6]->bh hi
    const int flat = blockIdx.y * 8 + blockIdx.x;
    const int qt = (flat >> 3) & 7;
    const int bh = (flat & 7) + ((flat >> 6) << 3);
    const int q0 = qt * 256;
    const size_t qkbase = (size_t)bh * NL * 64;

    const int rsub = lane >> 3;                            // 0..7
    const int scg  = (lane & 7) ^ rsub;                    // swizzled global chunk

    // preloop: stage Q (256x64, through upper smem region) + prefetch chunk 0
    u16 (*Qtmp)[64] = (u16(*)[64])(smem + 32768);
#pragma unroll
    for (int j = 0; j < 4; ++j)
        gload_lds16(&Q[qkbase + (size_t)(q0 + wave * 32 + j * 8 + rsub) * 64 + scg * 8],
                    &Qtmp[wave * 32 + j * 8][0]);
    const u16* kptr = Kg + qkbase + (size_t)(wave * 8 + rsub) * 64 + scg * 8;
    const u16* vptr = VT + qkbase + (size_t)(wave * 8 + rsub) * NL + scg * 8;
    gload_lds16(kptr, &KsB[0][wave * 8][0]);
    gload_lds16(vptr, &VsB[0][wave * 8][0]);
    kptr += 64 * 64;
    vptr += 64;
    __syncthreads();                      // Q + chunk0 resident
    bf16x8 bq[2][2];                      // Q frags: invariant across chunks
#pragma unroll
    for (int qh = 0; qh < 2; ++qh)
#pragma unroll
        for (int ks = 0; ks < 2; ++ks)
            bq[qh][ks] = *(const bf16x8*)
                &Qtmp[wave * 32 + qh * 16 + lq][(((ks << 2) | quad) ^ (lq & 7)) << 3];

    const bf16x8 ones = (bf16x8)(short)16256;              // bf16 1.0 splat
    f32x4 ot[2][4];                       // O^T rows d = mt*16+quad*4+r
#pragma unroll
    for (int qh = 0; qh < 2; ++qh)
#pragma unroll
        for (int mt = 0; mt < 4; ++mt) ot[qh][mt] = (f32x4)0.0f;
    f32x4 lacc[2] = {(f32x4)0.0f, (f32x4)0.0f};

    for (int kc = 0; kc < NL / 64; ++kc) {
        __syncthreads();                  // prev chunk consumed; prefetch landed
        if (kc < NL / 64 - 1) {
            gload_lds16(kptr, &KsB[(kc + 1) & 1][wave * 8][0]);
            gload_lds16(vptr, &VsB[(kc + 1) & 1][wave * 8][0]);
            kptr += 64 * 64;
            vptr += 64;
        }
        const int cur = kc & 1;

        // S^T = K_chunk (64k x 64d) . Q^T (64d x 32q); K frag feeds both halves
        f32x4 st[2][4];
#pragma unroll
        for (int qh = 0; qh < 2; ++qh)
#pragma unroll
            for (int mt = 0; mt < 4; ++mt) st[qh][mt] = (f32x4)0.0f;
#pragma unroll
        for (int ks = 0; ks < 2; ++ks)
#pragma unroll
            for (int mt = 0; mt < 4; ++mt) {
                bf16x8 ak = *(const bf16x8*)
                    &KsB[cur][mt * 16 + lq][(((ks << 2) | quad) ^ (lq & 7)) << 3];
                st[0][mt] = __builtin_amdgcn_mfma_f32_16x16x32_bf16(ak, bq[0][ks], st[0][mt], 0, 0, 0);
                st[1][mt] = __builtin_amdgcn_mfma_f32_16x16x32_bf16(ak, bq[1][ks], st[1][mt], 0, 0, 0);
            }

        // p = exp2(s); trunc-pack; in-register quad exchange -> PV B-operands.
        // st holds P^T[key=mt*16+quad*4+r][q=lq]; B-frag needs key=ks*32+quad*8+j.
        // Target quad q needs w{0,1}[2ks+(q>>1)] from source quads (q&1)*2,+1;
        // quad_xchg(a=w_[2ks], b=w_[2ks+1]) delivers exactly:
        //   a' = {a.q0, a.q2, b.q0, b.q2},  b' = {a.q1, a.q3, b.q1, b.q3}.
        bf16x8 bp[2][2];                  // [qh][ks]
#pragma unroll
        for (int qh = 0; qh < 2; ++qh) {
            u32 w0[4], w1[4];
#pragma unroll
            for (int mt = 0; mt < 4; ++mt) {
                float p0 = EXP2F(st[qh][mt][0]);
                float p1 = EXP2F(st[qh][mt][1]);
                float p2 = EXP2F(st[qh][mt][2]);
                float p3 = EXP2F(st[qh][mt][3]);
                w0[mt] = pkt(p0, p1);
                w1[mt] = pkt(p2, p3);
            }
#pragma unroll
            for (int ks = 0; ks < 2; ++ks) {
                u32 a0 = w0[2 * ks], b0 = w0[2 * ks + 1];
                u32 a1 = w1[2 * ks], b1 = w1[2 * ks + 1];
                quad_xchg(a0, b0);
                quad_xchg(a1, b1);
                union { u32 u[4]; bf16x8 v; } bb;
                bb.u[0] = a0;             // keys quad*8 + 0,1
                bb.u[1] = a1;             // keys quad*8 + 2,3
                bb.u[2] = b0;             // keys quad*8 + 4,5
                bb.u[3] = b1;             // keys quad*8 + 6,7
                bp[qh][ks] = bb.v;
            }
        }

        // O^T += V^T_chunk . P^T ; L += ones . P^T; V frag feeds both halves
#pragma unroll
        for (int ks = 0; ks < 2; ++ks) {
            lacc[0] = __builtin_amdgcn_mfma_f32_16x16x32_bf16(ones, bp[0][ks], lacc[0], 0, 0, 0);
            lacc[1] = __builtin_amdgcn_mfma_f32_16x16x32_bf16(ones, bp[1][ks], lacc[1], 0, 0, 0);
#pragma unroll
            for (int mt = 0; mt < 4; ++mt) {
                bf16x8 av = *(const bf16x8*)
                    &VsB[cur][mt * 16 + lq][(((ks << 2) | quad) ^ (lq & 7)) << 3];
                ot[0][mt] = __builtin_amdgcn_mfma_f32_16x16x32_bf16(av, bp[0][ks], ot[0][mt], 0, 0, 0);
                ot[1][mt] = __builtin_amdgcn_mfma_f32_16x16x32_bf16(av, bp[1][ks], ot[1][mt], 0, 0, 0);
            }
        }
    }

    // epilogue: transpose O^T through LDS, one 16-q half at a time
    __syncthreads();
    float* OT_ls = (float*)(smem + wave * 4352);     // [64 d][17] floats, per wave
    float* Ls_ls = (float*)(smem + 34816);           // 8 waves x 16 q
    const int b = bh >> 4, h = bh & 15;
    const int qq = lane >> 2, dblk = lane & 3;       // 16 rows x 4 d-blocks
#pragma unroll
    for (int qh = 0; qh < 2; ++qh) {
#pragma unroll
        for (int mt = 0; mt < 4; ++mt)
#pragma unroll
            for (int r = 0; r < 4; ++r)
                OT_ls[(mt * 16 + quad * 4 + r) * 17 + lq] = ot[qh][mt][r];
        if (quad == 0) Ls_ls[wave * 16 + lq] = lacc[qh][0];
        __builtin_amdgcn_s_waitcnt(0xc07f);          // intra-wave LDS RAW

        float rls = 1.0f / Ls_ls[wave * 16 + qq];
        u16 tmp[16];
#pragma unroll
        for (int e = 0; e < 16; ++e)
            tmp[e] = f2bf(OT_ls[(dblk * 16 + e) * 17 + qq] * rls);
        size_t orow = (size_t)b * NL + q0 + wave * 32 + qh * 16 + qq;
        size_t obase = orow * 1024 + h * 64 + dblk * 16;
        *(uint4*)&Og[obase] = *(uint4*)&tmp[0];
        *(uint4*)&Og[obase + 8] = *(uint4*)&tmp[8];
    }
}

// ----------------------------------------------------------------- launch
extern "C" void kernel_launch(void* const* d_in, const int* in_sizes, int n_in,
                              void* d_out, int out_size, void* d_ws, size_t ws_size,
                              hipStream_t stream) {
    const float* x     = (const float*)d_in[0];   // [8192][1024] fp32
    const float* Wqkv  = (const float*)d_in[1];   // [3072][1024] fp32
    const float* Wproj = (const float*)d_in[2];   // [1024][1024] fp32
    float* out = (float*)d_out;                   // [8192][1024] fp32

    char* ws = (char*)d_ws;
    u16* qkv     = (u16*)ws;                      // 50,331,648 B
    u16* attnout = (u16*)ws;                      // reuses qkv region (dead by then)
    u16* Qw      = (u16*)(ws + 50331648);         // 16,777,216 B
    u16* Kw      = (u16*)(ws + 67108864);         // 16,777,216 B
    u16* VTw     = (u16*)(ws + 83886080);         // 16,777,216 B
    float* cosT  = (float*)(ws + 100663296);      //    262,144 B
    float* sinT  = (float*)(ws + 100925440);      //    262,144 B
    u16* x_bf    = (u16*)(ws + 101187584);        // 16,777,216 B
    u16* Wqkv_bf = (u16*)(ws + 117964800);        //  6,291,456 B
    u16* Wproj_bf= (u16*)(ws + 124256256);        //  2,097,152 B  (total ~126.4 MB)

    rope_table_k<<<256, 256, 0, stream>>>(cosT, sinT);
    cast_all_k<<<12288, 256, 0, stream>>>(x, Wqkv, Wproj, x_bf, Wqkv_bf, Wproj_bf);
    gemm256_bt<<<dim3(12, 32), 512, 0, stream>>>(x_bf, Wqkv_bf, qkv, 8192, 3072, 1024);
    rope_vt_k<<<dim3(32, 64), 256, 0, stream>>>(qkv, cosT, sinT, Qw, Kw, VTw);
    attn_k<<<dim3(8, 64), 512, 0, stream>>>(Qw, Kw, VTw, attnout);
    gemm_bt<float><<<dim3(8, 64), 256, 0, stream>>>(attnout, Wproj_bf, out, 8192, 1024, 1024);
}